// Round 10
// baseline (10290.109 us; speedup 1.0000x reference)
//
#include <hip/hip_runtime.h>
#include <hip/hip_bf16.h>

typedef __hip_bfloat16 bf16;

#define KK 512    // kept tokens (epoch=20 -> ratio 0.5, K = 1024/2)

// ---- static device scratch (outside all harness buffers) ----
__device__ float g_xm[1048576];        // (B,C,H,W) router mean
__device__ float g_h1[262144];         // (B,32,H,W) router hidden
__device__ float g_scal[4096];         // (B,K) STE scale
__device__ int   g_idx[4096];          // (B,K) selected spatial indices (sorted)
__device__ float g_zs[4194304];        // (B*T, K, C) mamba output (fp32)

__device__ __forceinline__ float b2f(bf16 v) { return __bfloat162float(v); }

// ---------------- P1: init tables with valid defaults (defensive) ----------------
__global__ void t_init(int dummy) {
    int e = blockIdx.x * 256 + threadIdx.x;
    if (e < 4096) { g_scal[e] = 1.0f; g_idx[e] = e & 511; }
}

// ---------------- K1: xm = mean over T of x_in ----------------
__global__ void k_mean(const float* __restrict__ x) {
    int id = blockIdx.x * 256 + threadIdx.x;      // < 8*128*1024
    int n = id & 1023;
    int c = (id >> 10) & 127;
    int b = id >> 17;
    float s = 0.f;
#pragma unroll
    for (int t = 0; t < 8; ++t)
        s += x[(((b * 8 + t) * 128 + c) << 10) + n];
    g_xm[id] = s * 0.125f;
}

// ---------------- K2: 3x3 conv 128->32 + bias + LeakyReLU ----------------
__global__ void k_router_conv(const float* __restrict__ w, const float* __restrict__ bias) {
    int id = blockIdx.x * 256 + threadIdx.x;      // < 8*32*1024
    int x = id & 31;
    int y = (id >> 5) & 31;
    int oc = (id >> 10) & 31;
    int b = id >> 15;
    const float* xb = g_xm + b * 131072;
    float acc = bias[oc];
    for (int ic = 0; ic < 128; ++ic) {
        const float* wr = w + (oc * 128 + ic) * 9;
        const float* xr = xb + ic * 1024;
#pragma unroll
        for (int ky = 0; ky < 3; ++ky) {
            int yy = y + ky - 1;
            if (yy < 0 || yy > 31) continue;
#pragma unroll
            for (int kx = 0; kx < 3; ++kx) {
                int xx = x + kx - 1;
                if (xx < 0 || xx > 31) continue;
                acc += xr[yy * 32 + xx] * wr[ky * 3 + kx];
            }
        }
    }
    g_h1[id] = acc >= 0.f ? acc : 0.01f * acc;
}

// -------- K3: 1x1 conv + sigmoid + exact top-k(512) into g_idx/g_scal --------
__global__ __launch_bounds__(1024) void k_topk(const float* __restrict__ r2w,
                                               const float* __restrict__ r2b) {
    __shared__ float sc[1024];
    __shared__ int flg[1024];
    int b = blockIdx.x;
    int n = threadIdx.x;
    float a = r2b[0];
#pragma unroll
    for (int ic = 0; ic < 32; ++ic)
        a += g_h1[b * 32768 + ic * 1024 + n] * r2w[ic];
    float s = 1.f / (1.f + expf(-a));
    sc[n] = s;
    __syncthreads();
    // jax top_k tie-breaking (lower index wins) -> rank is a permutation of 0..1023
    int rank = 0;
    for (int j = 0; j < 1024; ++j) {
        float v = sc[j];
        rank += (v > s) || (v == s && j < n);
    }
    int sel = rank < KK ? 1 : 0;
    flg[n] = sel;
    __syncthreads();
    for (int d = 1; d < 1024; d <<= 1) {          // inclusive Hillis-Steele scan
        int add = (n >= d) ? flg[n - d] : 0;
        __syncthreads();
        flg[n] += add;
        __syncthreads();
    }
    if (sel) {
        int pos = (flg[n] - 1) & 511;             // clamped (exact when no NaN)
        g_idx[b * KK + pos] = n;
        g_scal[b * KK + pos] = s / (s + 1e-6f);
    }
}

// ---------------- K4: out = x_in everywhere (fp32; unselected final) ----------------
__global__ void k_copy(const float4* __restrict__ src, float4* __restrict__ dst) {
    int id = blockIdx.x * 256 + threadIdx.x;      // 2,097,152 float4 = 8,388,608 f32
    dst[id] = src[id];
}

// ---------------- K5: fused Mamba per (b,k); zs -> g_zs (fp32) ----------------
__global__ void k_mamba(const float* __restrict__ x_in, const float* __restrict__ norm1_w,
                        const float* __restrict__ w_in, const float* __restrict__ conv_w,
                        const float* __restrict__ conv_b, const float* __restrict__ w_xp,
                        const float* __restrict__ w_dt, const float* __restrict__ b_dt,
                        const float* __restrict__ A_log, const float* __restrict__ Dp,
                        const float* __restrict__ w_out) {
    __shared__ float zb[8][128];
    __shared__ float xz[8][512];
    __shared__ float xcv[8][256];
    __shared__ float xdbl[8][40];
    __shared__ float dtb[8][256];
    int tid = threadIdx.x;
    int blk = blockIdx.x;
    int b = blk >> 9;
    int k = blk & 511;
    int n = g_idx[b * KK + k] & 1023;
    float scl = fminf(fmaxf(g_scal[b * KK + k], 0.f), 1.f);

#pragma unroll
    for (int r = 0; r < 4; ++r) {
        int e = tid + r * 256;
        int t = e >> 7, c = e & 127;
        zb[t][c] = x_in[(((b * 8 + t) * 128 + c) << 10) + n] * scl;
    }
    __syncthreads();

    {   // rmsnorm
        int t = tid >> 5, lane = tid & 31;
        float ss = 0.f;
#pragma unroll
        for (int j = 0; j < 4; ++j) { float v = zb[t][lane * 4 + j]; ss += v * v; }
#pragma unroll
        for (int off = 16; off; off >>= 1) ss += __shfl_down(ss, off, 32);
        ss = __shfl(ss, 0, 32);
        float rstd = rsqrtf(ss * (1.f / 128.f) + 1e-5f);
#pragma unroll
        for (int j = 0; j < 4; ++j) {
            int c = lane * 4 + j;
            zb[t][c] = zb[t][c] * rstd * norm1_w[c];
        }
    }
    __syncthreads();

#pragma unroll
    for (int r = 0; r < 16; ++r) {                // in_proj (8,128)@(512,128)^T
        int e = tid + r * 256;
        int t = e >> 9, j = e & 511;
        const float* wr = w_in + j * 128;
        float acc = 0.f;
        for (int c = 0; c < 128; ++c) acc += zb[t][c] * wr[c];
        xz[t][j] = acc;
    }
    __syncthreads();

    {   // causal depthwise conv (k=4, left pad 3) + bias + silu
        int d = tid;
        float w0 = conv_w[d * 4 + 0], w1 = conv_w[d * 4 + 1];
        float w2 = conv_w[d * 4 + 2], w3 = conv_w[d * 4 + 3];
        float cb = conv_b[d];
        float x0 = 0.f, x1 = 0.f, x2 = 0.f;
#pragma unroll
        for (int t = 0; t < 8; ++t) {
            float x3 = xz[t][d];
            float v = x0 * w0 + x1 * w1 + x2 * w2 + x3 * w3 + cb;
            v = v / (1.f + expf(-v));
            xcv[t][d] = v;
            x0 = x1; x1 = x2; x2 = x3;
        }
    }
    __syncthreads();

#pragma unroll
    for (int r = 0; r < 2; ++r) {                 // x_proj (8,256)@(40,256)^T
        int e = tid + r * 256;
        if (e < 320) {
            int t = e / 40, j = e % 40;
            const float* wr = w_xp + j * 256;
            float acc = 0.f;
            for (int c = 0; c < 256; ++c) acc += xcv[t][c] * wr[c];
            xdbl[t][j] = acc;
        }
    }
    __syncthreads();

    {   // dt_proj + softplus
        int d = tid;
        float wr[8];
#pragma unroll
        for (int r = 0; r < 8; ++r) wr[r] = w_dt[d * 8 + r];
        float bb = b_dt[d];
#pragma unroll
        for (int t = 0; t < 8; ++t) {
            float acc = bb;
#pragma unroll
            for (int r = 0; r < 8; ++r) acc += xdbl[t][r] * wr[r];
            dtb[t][d] = acc > 20.f ? acc : logf(1.f + expf(acc));
        }
    }
    __syncthreads();

    {   // selective scan, 16 states in registers
        int d = tid;
        float A[16], h[16];
#pragma unroll
        for (int s = 0; s < 16; ++s) { A[s] = -expf(A_log[d * 16 + s]); h[s] = 0.f; }
        float Dd = Dp[d];
#pragma unroll
        for (int t = 0; t < 8; ++t) {
            float dtv = dtb[t][d];
            float u = xcv[t][d];
            float db = dtv * u;
            float y = 0.f;
#pragma unroll
            for (int s = 0; s < 16; ++s) {
                h[s] = h[s] * expf(dtv * A[s]) + db * xdbl[t][8 + s];
                y += h[s] * xdbl[t][24 + s];
            }
            y += u * Dd;
            float zg = xz[t][256 + d];
            y *= zg / (1.f + expf(-zg));
            xcv[t][d] = y;
        }
    }
    __syncthreads();

    // out_proj (8,256)@(128,256)^T -> g_zs[(b*8+t)*65536 + k*128 + i]
#pragma unroll
    for (int r = 0; r < 4; ++r) {
        int e = tid + r * 256;
        int t = e >> 7, i = e & 127;
        const float* wr = w_out + i * 256;
        float acc = 0.f;
        for (int c = 0; c < 256; ++c) acc += xcv[t][c] * wr[c];
        g_zs[((b * 8 + t) * 512 + k) * 128 + i] = acc;
    }
}

// ---- K6: fused qkv + 4-head attention + out_proj + residual + LN, per plane bt ----
// Writes ONLY selected columns of d_out (fp32); rest already = x_in via k_copy.
__global__ __launch_bounds__(512) void k_attn(const float* __restrict__ x_in,
                       float* __restrict__ out,
                       const float* __restrict__ wi, const float* __restrict__ bi,
                       const float* __restrict__ wo, const float* __restrict__ bo,
                       const float* __restrict__ ln_w, const float* __restrict__ ln_b) {
    __shared__ bf16 kb[256][32];
    __shared__ bf16 vb[256][32];
    int bt = blockIdx.x;                          // 64 planes
    int b = bt >> 3;
    int tid = threadIdx.x;                        // token k = tid
    const float* Z = g_zs + (size_t)bt * 65536;   // (k,c) linear
    int n_sel = g_idx[b * KK + tid] & 1023;
    const float rs = 0.17677669529663687f;        // 1/sqrt(32)

    float y[128];
#pragma unroll
    for (int i = 0; i < 128; ++i) y[i] = bo[i];   // out_proj bias

    for (int h = 0; h < 4; ++h) {
        float qv[32];
#pragma unroll 4
        for (int c = 0; c < 32; ++c) {            // q projection for my token
            const float* wq = wi + (h * 32 + c) * 128;
            float a = bi[h * 32 + c];
            for (int j = 0; j < 128; ++j) a += Z[tid * 128 + j] * wq[j];
            qv[c] = a * rs;
        }
        float m = -1e30f, l = 0.f, acc[32];
#pragma unroll
        for (int c = 0; c < 32; ++c) acc[c] = 0.f;

        for (int chunk = 0; chunk < 2; ++chunk) {
            __syncthreads();                      // prev-chunk readers done
            {   // stage K (tid<256) / V (tid>=256) for this chunk's 256 tokens
                int ti = tid & 255;
                int tok = chunk * 256 + ti;
                int wbase = (tid < 256) ? (128 + h * 32) : (256 + h * 32);
                for (int c = 0; c < 32; ++c) {
                    const float* wrow = wi + (wbase + c) * 128;
                    float a = bi[wbase + c];
                    for (int j = 0; j < 128; ++j) a += Z[tok * 128 + j] * wrow[j];
                    if (tid < 256) kb[ti][c] = __float2bfloat16(a);
                    else           vb[ti][c] = __float2bfloat16(a);
                }
            }
            __syncthreads();
            float mc = -1e30f;
            for (int kk = 0; kk < 256; ++kk) {
                float s = 0.f;
#pragma unroll
                for (int c = 0; c < 32; ++c) s += qv[c] * b2f(kb[kk][c]);
                mc = fmaxf(mc, s);
            }
            float mn = fmaxf(m, mc);
            float rsc = expf(m - mn);
            l *= rsc;
#pragma unroll
            for (int c = 0; c < 32; ++c) acc[c] *= rsc;
            for (int kk = 0; kk < 256; ++kk) {
                float s = 0.f;
#pragma unroll
                for (int c = 0; c < 32; ++c) s += qv[c] * b2f(kb[kk][c]);
                float e2 = expf(s - mn);
                l += e2;
#pragma unroll
                for (int c = 0; c < 32; ++c) acc[c] += e2 * b2f(vb[kk][c]);
            }
            m = mn;
        }
        float inv = 1.f / l;
        for (int i = 0; i < 128; ++i) {           // out_proj partial
            const float* wr = wo + i * 128 + h * 32;
            float t2 = 0.f;
#pragma unroll
            for (int c = 0; c < 32; ++c) t2 += acc[c] * wr[c];
            y[i] += t2 * inv;
        }
    }

    // residual + thread-local LayerNorm
    float s1 = 0.f, s2 = 0.f;
#pragma unroll
    for (int i = 0; i < 128; ++i) {
        float xi = y[i] + Z[tid * 128 + i];
        y[i] = xi;
        s1 += xi; s2 += xi * xi;
    }
    float mu = s1 * (1.f / 128.f);
    float var = s2 * (1.f / 128.f) - mu * mu;
    float rstd = rsqrtf(fmaxf(var, 0.f) + 1e-5f);

    float* P = out + (size_t)bt * 131072;
    const float* XP = x_in + (size_t)bt * 131072;
#pragma unroll 4
    for (int i = 0; i < 128; ++i) {
        float yo = (y[i] - mu) * rstd * ln_w[i] + ln_b[i];
        yo = fminf(fmaxf(yo, -1e4f), 1e4f);       // NaN scrub (no-op when sane)
        P[i * 1024 + n_sel] = XP[i * 1024 + n_sel] + yo;
    }
}

extern "C" void kernel_launch(void* const* d_in, const int* in_sizes, int n_in,
                              void* d_out, int out_size, void* d_ws, size_t ws_size,
                              hipStream_t stream) {
    const float* x_in      = (const float*)d_in[0];
    const float* norm1_w   = (const float*)d_in[1];
    const float* in_proj_w = (const float*)d_in[2];
    const float* conv1d_w  = (const float*)d_in[3];
    const float* conv1d_b  = (const float*)d_in[4];
    const float* x_proj_w  = (const float*)d_in[5];
    const float* dt_proj_w = (const float*)d_in[6];
    const float* dt_proj_b = (const float*)d_in[7];
    const float* A_log     = (const float*)d_in[8];
    const float* Dp        = (const float*)d_in[9];
    const float* out_proj_w= (const float*)d_in[10];
    const float* r1_w      = (const float*)d_in[11];
    const float* r1_b      = (const float*)d_in[12];
    const float* r2_w      = (const float*)d_in[13];
    const float* r2_b      = (const float*)d_in[14];
    const float* attn_in_w = (const float*)d_in[15];
    const float* attn_in_b = (const float*)d_in[16];
    const float* attn_out_w= (const float*)d_in[17];
    const float* attn_out_b= (const float*)d_in[18];
    const float* ln_w      = (const float*)d_in[19];
    const float* ln_b      = (const float*)d_in[20];
    // d_in[21]: current_epoch == 20 (static) -> ratio 0.5 -> K = 512
    // ALL tensors fp32 (in AND out). d_ws untouched; scratch in __device__ globals.

    float* out = (float*)d_out;

    t_init<<<16, 256, 0, stream>>>(0);
    k_mean<<<4096, 256, 0, stream>>>(x_in);
    k_router_conv<<<1024, 256, 0, stream>>>(r1_w, r1_b);
    k_topk<<<8, 1024, 0, stream>>>(r2_w, r2_b);
    k_copy<<<8192, 256, 0, stream>>>((const float4*)x_in, (float4*)d_out);
    k_mamba<<<4096, 256, 0, stream>>>(x_in, norm1_w, in_proj_w, conv1d_w, conv1d_b,
                                      x_proj_w, dt_proj_w, dt_proj_b, A_log, Dp,
                                      out_proj_w);
    k_attn<<<64, 512, 0, stream>>>(x_in, out, attn_in_w, attn_in_b,
                                   attn_out_w, attn_out_b, ln_w, ln_b);
}

// Round 11
// 7739.494 us; speedup vs baseline: 1.3296x; 1.3296x over previous
//
#include <hip/hip_runtime.h>
#include <hip/hip_bf16.h>

typedef __hip_bfloat16 bf16;

#define KK 512    // kept tokens (epoch=20 -> ratio 0.5, K = 1024/2)

// ---- static device scratch (outside all harness buffers) ----
__device__ float g_xm[1048576];        // (B,C,H,W) router mean
__device__ float g_h1[262144];         // (B,32,H,W) router hidden
__device__ float g_scal[4096];         // (B,K) STE scale
__device__ int   g_idx[4096];          // (B,K) selected spatial indices (sorted)
__device__ float g_zs[4194304];        // (B*T, K, C) mamba output
__device__ float g_qkv[12582912];      // (B*T, K, 384) attn qkv
__device__ float g_o[4194304];         // (B*T, K, C) attn context

__device__ __forceinline__ float b2f(bf16 v) { return __bfloat162float(v); }

// ---------------- P1: init tables with valid defaults (defensive) ----------------
__global__ void t_init(int dummy) {
    int e = blockIdx.x * 256 + threadIdx.x;
    if (e < 4096) { g_scal[e] = 1.0f; g_idx[e] = e & 511; }
}

// ---------------- K1: xm = mean over T of x_in ----------------
__global__ void k_mean(const float* __restrict__ x) {
    int id = blockIdx.x * 256 + threadIdx.x;      // < 8*128*1024
    int n = id & 1023;
    int c = (id >> 10) & 127;
    int b = id >> 17;
    float s = 0.f;
#pragma unroll
    for (int t = 0; t < 8; ++t)
        s += x[(((b * 8 + t) * 128 + c) << 10) + n];
    g_xm[id] = s * 0.125f;
}

// ---------------- K2: 3x3 conv 128->32 + bias + LeakyReLU ----------------
__global__ void k_router_conv(const float* __restrict__ w, const float* __restrict__ bias) {
    int id = blockIdx.x * 256 + threadIdx.x;      // < 8*32*1024
    int x = id & 31;
    int y = (id >> 5) & 31;
    int oc = (id >> 10) & 31;
    int b = id >> 15;
    const float* xb = g_xm + b * 131072;
    float acc = bias[oc];
    for (int ic = 0; ic < 128; ++ic) {
        const float* wr = w + (oc * 128 + ic) * 9;
        const float* xr = xb + ic * 1024;
#pragma unroll
        for (int ky = 0; ky < 3; ++ky) {
            int yy = y + ky - 1;
            if (yy < 0 || yy > 31) continue;
#pragma unroll
            for (int kx = 0; kx < 3; ++kx) {
                int xx = x + kx - 1;
                if (xx < 0 || xx > 31) continue;
                acc += xr[yy * 32 + xx] * wr[ky * 3 + kx];
            }
        }
    }
    g_h1[id] = acc >= 0.f ? acc : 0.01f * acc;
}

// -------- K3: 1x1 conv + sigmoid + exact top-k(512) into g_idx/g_scal --------
__global__ __launch_bounds__(1024) void k_topk(const float* __restrict__ r2w,
                                               const float* __restrict__ r2b) {
    __shared__ float sc[1024];
    __shared__ int flg[1024];
    int b = blockIdx.x;
    int n = threadIdx.x;
    float a = r2b[0];
#pragma unroll
    for (int ic = 0; ic < 32; ++ic)
        a += g_h1[b * 32768 + ic * 1024 + n] * r2w[ic];
    float s = 1.f / (1.f + expf(-a));
    sc[n] = s;
    __syncthreads();
    // jax top_k tie-breaking (lower index wins) -> rank is a permutation of 0..1023
    int rank = 0;
    for (int j = 0; j < 1024; ++j) {
        float v = sc[j];
        rank += (v > s) || (v == s && j < n);
    }
    int sel = rank < KK ? 1 : 0;
    flg[n] = sel;
    __syncthreads();
    for (int d = 1; d < 1024; d <<= 1) {          // inclusive Hillis-Steele scan
        int add = (n >= d) ? flg[n - d] : 0;
        __syncthreads();
        flg[n] += add;
        __syncthreads();
    }
    if (sel) {
        int pos = (flg[n] - 1) & 511;
        g_idx[b * KK + pos] = n;
        g_scal[b * KK + pos] = s / (s + 1e-6f);
    }
}

// ---------------- K4: out = x_in everywhere (unselected final) ----------------
__global__ void k_copy(const float4* __restrict__ src, float4* __restrict__ dst) {
    int id = blockIdx.x * 256 + threadIdx.x;      // 2,097,152 float4
    dst[id] = src[id];
}

// ---------------- K5: fused Mamba per (b,k); zs -> g_zs ----------------
// __launch_bounds__(256,2): 128-VGPR budget so A[16]/h[16] stay in registers (no spill)
__global__ __launch_bounds__(256, 2) void k_mamba(
                        const float* __restrict__ x_in, const float* __restrict__ norm1_w,
                        const float* __restrict__ w_in, const float* __restrict__ conv_w,
                        const float* __restrict__ conv_b, const float* __restrict__ w_xp,
                        const float* __restrict__ w_dt, const float* __restrict__ b_dt,
                        const float* __restrict__ A_log, const float* __restrict__ Dp,
                        const float* __restrict__ w_out) {
    __shared__ float zb[8][128];
    __shared__ float xz[8][512];
    __shared__ float xcv[8][256];
    __shared__ float xdbl[8][40];
    __shared__ float dtb[8][256];
    int tid = threadIdx.x;
    int blk = blockIdx.x;
    int b = blk >> 9;
    int k = blk & 511;
    int n = g_idx[b * KK + k] & 1023;
    float scl = fminf(fmaxf(g_scal[b * KK + k], 0.f), 1.f);

#pragma unroll
    for (int r = 0; r < 4; ++r) {
        int e = tid + r * 256;
        int t = e >> 7, c = e & 127;
        zb[t][c] = x_in[(((b * 8 + t) * 128 + c) << 10) + n] * scl;
    }
    __syncthreads();

    {   // rmsnorm
        int t = tid >> 5, lane = tid & 31;
        float ss = 0.f;
#pragma unroll
        for (int j = 0; j < 4; ++j) { float v = zb[t][lane * 4 + j]; ss += v * v; }
#pragma unroll
        for (int off = 16; off; off >>= 1) ss += __shfl_down(ss, off, 32);
        ss = __shfl(ss, 0, 32);
        float rstd = rsqrtf(ss * (1.f / 128.f) + 1e-5f);
#pragma unroll
        for (int j = 0; j < 4; ++j) {
            int c = lane * 4 + j;
            zb[t][c] = zb[t][c] * rstd * norm1_w[c];
        }
    }
    __syncthreads();

#pragma unroll
    for (int r = 0; r < 16; ++r) {                // in_proj (8,128)@(512,128)^T
        int e = tid + r * 256;
        int t = e >> 9, j = e & 511;
        const float* wr = w_in + j * 128;
        float acc = 0.f;
        for (int c = 0; c < 128; ++c) acc += zb[t][c] * wr[c];
        xz[t][j] = acc;
    }
    __syncthreads();

    {   // causal depthwise conv (k=4, left pad 3) + bias + silu
        int d = tid;
        float w0 = conv_w[d * 4 + 0], w1 = conv_w[d * 4 + 1];
        float w2 = conv_w[d * 4 + 2], w3 = conv_w[d * 4 + 3];
        float cb = conv_b[d];
        float x0 = 0.f, x1 = 0.f, x2 = 0.f;
#pragma unroll
        for (int t = 0; t < 8; ++t) {
            float x3 = xz[t][d];
            float v = x0 * w0 + x1 * w1 + x2 * w2 + x3 * w3 + cb;
            v = v / (1.f + expf(-v));
            xcv[t][d] = v;
            x0 = x1; x1 = x2; x2 = x3;
        }
    }
    __syncthreads();

#pragma unroll
    for (int r = 0; r < 2; ++r) {                 // x_proj (8,256)@(40,256)^T
        int e = tid + r * 256;
        if (e < 320) {
            int t = e / 40, j = e % 40;
            const float* wr = w_xp + j * 256;
            float acc = 0.f;
            for (int c = 0; c < 256; ++c) acc += xcv[t][c] * wr[c];
            xdbl[t][j] = acc;
        }
    }
    __syncthreads();

    {   // dt_proj + softplus
        int d = tid;
        float bb = b_dt[d];
#pragma unroll
        for (int t = 0; t < 8; ++t) {
            float acc = bb;
#pragma unroll
            for (int r = 0; r < 8; ++r) acc += xdbl[t][r] * w_dt[d * 8 + r];
            dtb[t][d] = acc > 20.f ? acc : logf(1.f + expf(acc));
        }
    }
    __syncthreads();

    {   // selective scan, 16 states in registers
        int d = tid;
        float A[16], h[16];
#pragma unroll
        for (int s = 0; s < 16; ++s) { A[s] = -expf(A_log[d * 16 + s]); h[s] = 0.f; }
        float Dd = Dp[d];
#pragma unroll
        for (int t = 0; t < 8; ++t) {
            float dtv = dtb[t][d];
            float u = xcv[t][d];
            float db = dtv * u;
            float y = 0.f;
#pragma unroll
            for (int s = 0; s < 16; ++s) {
                h[s] = h[s] * expf(dtv * A[s]) + db * xdbl[t][8 + s];
                y += h[s] * xdbl[t][24 + s];
            }
            y += u * Dd;
            float zg = xz[t][256 + d];
            y *= zg / (1.f + expf(-zg));
            xcv[t][d] = y;
        }
    }
    __syncthreads();

    // out_proj (8,256)@(128,256)^T -> g_zs
#pragma unroll
    for (int r = 0; r < 4; ++r) {
        int e = tid + r * 256;
        int t = e >> 7, i = e & 127;
        const float* wr = w_out + i * 256;
        float acc = 0.f;
        for (int c = 0; c < 256; ++c) acc += xcv[t][c] * wr[c];
        g_zs[((b * 8 + t) * 512 + k) * 128 + i] = acc;
    }
}

// ---------------- K6: qkv projection, 32 tokens per block ----------------
__global__ __launch_bounds__(256) void k_qkv(const float* __restrict__ wi,
                                             const float* __restrict__ bi) {
    __shared__ float zr[32][128];                 // 16 KB
    int tok0 = blockIdx.x * 32;                   // 1024 blocks
    int tid = threadIdx.x;
#pragma unroll
    for (int r = 0; r < 16; ++r) {
        int e = tid + r * 256;
        zr[e >> 7][e & 127] = g_zs[(size_t)tok0 * 128 + e];
    }
    __syncthreads();
#pragma unroll
    for (int pass = 0; pass < 2; ++pass) {
        int j = tid + pass * 256;
        if (j < 384) {
            const float* wr = wi + j * 128;
            float bv = bi[j];
            float acc[32];
#pragma unroll
            for (int t = 0; t < 32; ++t) acc[t] = bv;
            for (int c = 0; c < 128; ++c) {
                float wv = wr[c];
#pragma unroll
                for (int t = 0; t < 32; ++t) acc[t] += zr[t][c] * wv;
            }
#pragma unroll
            for (int t = 0; t < 32; ++t)
                g_qkv[(size_t)(tok0 + t) * 384 + j] = acc[t];
        }
    }
}

// ---------------- K7: attention per (bt, head); K/V bf16 in LDS ----------------
__global__ __launch_bounds__(512) void k_attn2() {
    __shared__ bf16 kb[512][32];
    __shared__ bf16 vb[512][32];
    int bt = blockIdx.x >> 2;
    int h = blockIdx.x & 3;
    int tid = threadIdx.x;                        // one q token per thread
    const float* Q = g_qkv + (size_t)bt * 512 * 384;
    const float rs = 0.17677669529663687f;        // 1/sqrt(32)

#pragma unroll
    for (int r = 0; r < 32; ++r) {
        int e = tid + r * 512;                    // 16384 = 512 tok × 32 col
        int tok = e >> 5, c = e & 31;
        kb[tok][c] = __float2bfloat16(Q[tok * 384 + 128 + h * 32 + c]);
        vb[tok][c] = __float2bfloat16(Q[tok * 384 + 256 + h * 32 + c]);
    }
    __syncthreads();

    float qv[32];
#pragma unroll
    for (int c = 0; c < 32; ++c) qv[c] = Q[tid * 384 + h * 32 + c] * rs;

    float m = -1e30f, l = 0.f, acc[32];
#pragma unroll
    for (int c = 0; c < 32; ++c) acc[c] = 0.f;
    for (int kk = 0; kk < 512; ++kk) {
        float s = 0.f;
#pragma unroll
        for (int c = 0; c < 32; ++c) s += qv[c] * b2f(kb[kk][c]);
        float mn = fmaxf(m, s);
        float rsc = expf(m - mn);
        float e2 = expf(s - mn);
        l = l * rsc + e2;
#pragma unroll
        for (int c = 0; c < 32; ++c) acc[c] = acc[c] * rsc + e2 * b2f(vb[kk][c]);
        m = mn;
    }
    float inv = 1.f / l;
    float* orow = g_o + ((size_t)bt * 512 + tid) * 128 + h * 32;
#pragma unroll
    for (int c = 0; c < 32; ++c) orow[c] = acc[c] * inv;
}

// ------- K8: out_proj + residual + LayerNorm + scatter (fp32 d_out) -------
__global__ __launch_bounds__(128) void k_final(const float* __restrict__ x_in,
                       float* __restrict__ out,
                       const float* __restrict__ wo, const float* __restrict__ bo,
                       const float* __restrict__ ln_w, const float* __restrict__ ln_b) {
    __shared__ float orow[128];
    __shared__ float sh[4];
    int tk = blockIdx.x;                          // bt*512 + k
    int bt = tk >> 9, k = tk & 511;
    int b = bt >> 3;
    int i = threadIdx.x;                          // 128 threads
    orow[i] = g_o[(size_t)tk * 128 + i];
    __syncthreads();
    const float* wr = wo + i * 128;
    float acc = bo[i];
    for (int j = 0; j < 128; ++j) acc += orow[j] * wr[j];
    float xi = g_zs[(size_t)tk * 128 + i] + acc;
    float s1 = xi, s2 = xi * xi;
#pragma unroll
    for (int off = 32; off; off >>= 1) {
        s1 += __shfl_down(s1, off, 64);
        s2 += __shfl_down(s2, off, 64);
    }
    if ((i & 63) == 0) { sh[(i >> 6) * 2] = s1; sh[(i >> 6) * 2 + 1] = s2; }
    __syncthreads();
    float mu = (sh[0] + sh[2]) * (1.f / 128.f);
    float var = (sh[1] + sh[3]) * (1.f / 128.f) - mu * mu;
    float yo = (xi - mu) * rsqrtf(fmaxf(var, 0.f) + 1e-5f) * ln_w[i] + ln_b[i];
    int n = g_idx[b * KK + k] & 1023;
    size_t oi = (((size_t)(bt * 128 + i)) << 10) + n;
    out[oi] = x_in[oi] + yo;
}

extern "C" void kernel_launch(void* const* d_in, const int* in_sizes, int n_in,
                              void* d_out, int out_size, void* d_ws, size_t ws_size,
                              hipStream_t stream) {
    const float* x_in      = (const float*)d_in[0];
    const float* norm1_w   = (const float*)d_in[1];
    const float* in_proj_w = (const float*)d_in[2];
    const float* conv1d_w  = (const float*)d_in[3];
    const float* conv1d_b  = (const float*)d_in[4];
    const float* x_proj_w  = (const float*)d_in[5];
    const float* dt_proj_w = (const float*)d_in[6];
    const float* dt_proj_b = (const float*)d_in[7];
    const float* A_log     = (const float*)d_in[8];
    const float* Dp        = (const float*)d_in[9];
    const float* out_proj_w= (const float*)d_in[10];
    const float* r1_w      = (const float*)d_in[11];
    const float* r1_b      = (const float*)d_in[12];
    const float* r2_w      = (const float*)d_in[13];
    const float* r2_b      = (const float*)d_in[14];
    const float* attn_in_w = (const float*)d_in[15];
    const float* attn_in_b = (const float*)d_in[16];
    const float* attn_out_w= (const float*)d_in[17];
    const float* attn_out_b= (const float*)d_in[18];
    const float* ln_w      = (const float*)d_in[19];
    const float* ln_b      = (const float*)d_in[20];
    // d_in[21]: current_epoch == 20 (static) -> ratio 0.5 -> K = 512

    float* out = (float*)d_out;

    t_init<<<16, 256, 0, stream>>>(0);
    k_mean<<<4096, 256, 0, stream>>>(x_in);
    k_router_conv<<<1024, 256, 0, stream>>>(r1_w, r1_b);
    k_topk<<<8, 1024, 0, stream>>>(r2_w, r2_b);
    k_copy<<<8192, 256, 0, stream>>>((const float4*)x_in, (float4*)d_out);
    k_mamba<<<4096, 256, 0, stream>>>(x_in, norm1_w, in_proj_w, conv1d_w, conv1d_b,
                                      x_proj_w, dt_proj_w, dt_proj_b, A_log, Dp,
                                      out_proj_w);
    k_qkv<<<1024, 256, 0, stream>>>(attn_in_w, attn_in_b);
    k_attn2<<<256, 512, 0, stream>>>();
    k_final<<<32768, 128, 0, stream>>>(x_in, out, attn_out_w, attn_out_b, ln_w, ln_b);
}

// Round 12
// 2572.025 us; speedup vs baseline: 4.0008x; 3.0091x over previous
//
#include <hip/hip_runtime.h>
#include <hip/hip_bf16.h>

typedef __hip_bfloat16 bf16;

#define KK 512    // kept tokens (epoch=20 -> ratio 0.5, K = 1024/2)

// ---- static device scratch (outside all harness buffers) ----
__device__ float g_xm[1048576];        // (B,C,H,W) router mean
__device__ float g_h1[262144];         // (B,32,H,W) router hidden
__device__ float g_scal[4096];         // (B,K) STE scale
__device__ int   g_idx[4096];          // (B,K) selected spatial indices (sorted)
__device__ float g_xg[4194304];        // (B,K,T,C) gathered+scaled tokens (dense)
__device__ float g_zs[4194304];        // (B*T, K, C) mamba output
__device__ float g_qkv[12582912];      // (B*T, K, 384) attn qkv
__device__ float g_o[4194304];         // (B*T, K, C) attn context

__device__ __forceinline__ float b2f(bf16 v) { return __bfloat162float(v); }

// ---------------- P1: init tables with valid defaults (defensive) ----------------
__global__ void t_init(int dummy) {
    int e = blockIdx.x * 256 + threadIdx.x;
    if (e < 4096) { g_scal[e] = 1.0f; g_idx[e] = e & 511; }
}

// ---------------- K1: xm = mean over T of x_in ----------------
__global__ void k_mean(const float* __restrict__ x) {
    int id = blockIdx.x * 256 + threadIdx.x;      // < 8*128*1024
    int n = id & 1023;
    int c = (id >> 10) & 127;
    int b = id >> 17;
    float s = 0.f;
#pragma unroll
    for (int t = 0; t < 8; ++t)
        s += x[(((b * 8 + t) * 128 + c) << 10) + n];
    g_xm[id] = s * 0.125f;
}

// ---------------- K2: 3x3 conv 128->32 + bias + LeakyReLU ----------------
__global__ void k_router_conv(const float* __restrict__ w, const float* __restrict__ bias) {
    int id = blockIdx.x * 256 + threadIdx.x;      // < 8*32*1024
    int x = id & 31;
    int y = (id >> 5) & 31;
    int oc = (id >> 10) & 31;
    int b = id >> 15;
    const float* xb = g_xm + b * 131072;
    float acc = bias[oc];
    for (int ic = 0; ic < 128; ++ic) {
        const float* wr = w + (oc * 128 + ic) * 9;
        const float* xr = xb + ic * 1024;
#pragma unroll
        for (int ky = 0; ky < 3; ++ky) {
            int yy = y + ky - 1;
            if (yy < 0 || yy > 31) continue;
#pragma unroll
            for (int kx = 0; kx < 3; ++kx) {
                int xx = x + kx - 1;
                if (xx < 0 || xx > 31) continue;
                acc += xr[yy * 32 + xx] * wr[ky * 3 + kx];
            }
        }
    }
    g_h1[id] = acc >= 0.f ? acc : 0.01f * acc;
}

// -------- K3: 1x1 conv + sigmoid + exact top-k(512) into g_idx/g_scal --------
__global__ __launch_bounds__(1024) void k_topk(const float* __restrict__ r2w,
                                               const float* __restrict__ r2b) {
    __shared__ float sc[1024];
    __shared__ int flg[1024];
    int b = blockIdx.x;
    int n = threadIdx.x;
    float a = r2b[0];
#pragma unroll
    for (int ic = 0; ic < 32; ++ic)
        a += g_h1[b * 32768 + ic * 1024 + n] * r2w[ic];
    float s = 1.f / (1.f + expf(-a));
    sc[n] = s;
    __syncthreads();
    // jax top_k tie-breaking (lower index wins) -> rank is a permutation of 0..1023
    int rank = 0;
    for (int j = 0; j < 1024; ++j) {
        float v = sc[j];
        rank += (v > s) || (v == s && j < n);
    }
    int sel = rank < KK ? 1 : 0;
    flg[n] = sel;
    __syncthreads();
    for (int d = 1; d < 1024; d <<= 1) {          // inclusive Hillis-Steele scan
        int add = (n >= d) ? flg[n - d] : 0;
        __syncthreads();
        flg[n] += add;
        __syncthreads();
    }
    if (sel) {
        int pos = (flg[n] - 1) & 511;
        g_idx[b * KK + pos] = n;
        g_scal[b * KK + pos] = s / (s + 1e-6f);
    }
}

// ---------------- K4: out = x_in everywhere (unselected final) ----------------
__global__ void k_copy(const float4* __restrict__ src, float4* __restrict__ dst) {
    int id = blockIdx.x * 256 + threadIdx.x;      // 2,097,152 float4
    dst[id] = src[id];
}

// ------ K4b: coalesced gather: g_xg[(b,k),(t,c)] = x_in[b,t,c,n(k)] * scl(k) ------
// block = (b, t, c-chunk of 16). Reads 16 rows of 4 KB coalesced into LDS,
// writes 64 B contiguous per thread. Removes the cache-hostile scatter from k_mamba.
__global__ __launch_bounds__(256) void k_gather(const float* __restrict__ x) {
    __shared__ float lds[16][1024];               // 64 KB
    int blk = blockIdx.x;                         // 512 = 8b * 8t * 8cc
    int cchunk = blk & 7;
    int t = (blk >> 3) & 7;
    int b = blk >> 6;
    int c0 = cchunk * 16;
    int tid = threadIdx.x;
    const float* src = x + ((size_t)(b * 8 + t) * 128 + c0) * 1024;
#pragma unroll
    for (int r = 0; r < 64; ++r) {
        int e = tid + r * 256;                    // 16384
        lds[e >> 10][e & 1023] = src[e];
    }
    __syncthreads();
#pragma unroll
    for (int half = 0; half < 2; ++half) {
        int k = tid + half * 256;
        int n = g_idx[b * KK + k] & 1023;
        float scl = fminf(fmaxf(g_scal[b * KK + k], 0.f), 1.f);
        float* dst = g_xg + ((size_t)(b * 512 + k) * 8 + t) * 128 + c0;
#pragma unroll
        for (int cc = 0; cc < 16; ++cc)
            dst[cc] = lds[cc][n] * scl;
    }
}

// ---------------- K5: fused Mamba per (b,k); dense g_xg in, g_zs out ----------------
__global__ __launch_bounds__(256, 2) void k_mamba(
                        const float* __restrict__ norm1_w,
                        const float* __restrict__ w_in, const float* __restrict__ conv_w,
                        const float* __restrict__ conv_b, const float* __restrict__ w_xp,
                        const float* __restrict__ w_dt, const float* __restrict__ b_dt,
                        const float* __restrict__ A_log, const float* __restrict__ Dp,
                        const float* __restrict__ w_out) {
    __shared__ float zb[8][128];
    __shared__ float xz[8][512];
    __shared__ float xcv[8][256];
    __shared__ float xdbl[8][40];
    int tid = threadIdx.x;
    int blk = blockIdx.x;                         // (b*512 + k)

    // dense coalesced load of this token's (T,C) block
#pragma unroll
    for (int r = 0; r < 4; ++r) {
        int e = tid + r * 256;
        zb[e >> 7][e & 127] = g_xg[(size_t)blk * 1024 + e];
    }
    __syncthreads();

    {   // rmsnorm
        int t = tid >> 5, lane = tid & 31;
        float ss = 0.f;
#pragma unroll
        for (int j = 0; j < 4; ++j) { float v = zb[t][lane * 4 + j]; ss += v * v; }
#pragma unroll
        for (int off = 16; off; off >>= 1) ss += __shfl_down(ss, off, 32);
        ss = __shfl(ss, 0, 32);
        float rstd = rsqrtf(ss * (1.f / 128.f) + 1e-5f);
#pragma unroll
        for (int j = 0; j < 4; ++j) {
            int c = lane * 4 + j;
            zb[t][c] = zb[t][c] * rstd * norm1_w[c];
        }
    }
    __syncthreads();

#pragma unroll
    for (int r = 0; r < 16; ++r) {                // in_proj (8,128)@(512,128)^T
        int e = tid + r * 256;
        int t = e >> 9, j = e & 511;
        const float4* wr = (const float4*)(w_in + j * 128);
        const float4* zr = (const float4*)zb[t];
        float acc = 0.f;
#pragma unroll 8
        for (int c = 0; c < 32; ++c) {
            float4 w4 = wr[c], z4 = zr[c];
            acc += z4.x * w4.x + z4.y * w4.y + z4.z * w4.z + z4.w * w4.w;
        }
        xz[t][j] = acc;
    }
    __syncthreads();

    {   // causal depthwise conv (k=4, left pad 3) + bias + silu
        int d = tid;
        float w0 = conv_w[d * 4 + 0], w1 = conv_w[d * 4 + 1];
        float w2 = conv_w[d * 4 + 2], w3 = conv_w[d * 4 + 3];
        float cb = conv_b[d];
        float x0 = 0.f, x1 = 0.f, x2 = 0.f;
#pragma unroll
        for (int t = 0; t < 8; ++t) {
            float x3 = xz[t][d];
            float v = x0 * w0 + x1 * w1 + x2 * w2 + x3 * w3 + cb;
            v = v / (1.f + expf(-v));
            xcv[t][d] = v;
            x0 = x1; x1 = x2; x2 = x3;
        }
    }
    __syncthreads();

#pragma unroll
    for (int r = 0; r < 2; ++r) {                 // x_proj (8,256)@(40,256)^T
        int e = tid + r * 256;
        if (e < 320) {
            int t = e / 40, j = e % 40;
            const float4* wr = (const float4*)(w_xp + j * 256);
            const float4* xr = (const float4*)xcv[t];
            float acc = 0.f;
#pragma unroll 8
            for (int c = 0; c < 64; ++c) {
                float4 w4 = wr[c], x4 = xr[c];
                acc += x4.x * w4.x + x4.y * w4.y + x4.z * w4.z + x4.w * w4.w;
            }
            xdbl[t][j] = acc;
        }
    }
    __syncthreads();

    {   // dt_proj + softplus (thread-local) + selective scan, 16 states in registers
        int d = tid;
        float wdt[8];
#pragma unroll
        for (int r = 0; r < 8; ++r) wdt[r] = w_dt[d * 8 + r];
        float bdt = b_dt[d];
        float A[16], h[16];
#pragma unroll
        for (int s = 0; s < 16; ++s) { A[s] = -expf(A_log[d * 16 + s]); h[s] = 0.f; }
        float Dd = Dp[d];
#pragma unroll
        for (int t = 0; t < 8; ++t) {
            float dtv = bdt;
#pragma unroll
            for (int r = 0; r < 8; ++r) dtv += xdbl[t][r] * wdt[r];
            dtv = dtv > 20.f ? dtv : logf(1.f + expf(dtv));
            float u = xcv[t][d];
            float db = dtv * u;
            float y = 0.f;
#pragma unroll
            for (int s = 0; s < 16; ++s) {
                h[s] = h[s] * expf(dtv * A[s]) + db * xdbl[t][8 + s];
                y += h[s] * xdbl[t][24 + s];
            }
            y += u * Dd;
            float zg = xz[t][256 + d];
            y *= zg / (1.f + expf(-zg));
            xcv[t][d] = y;
        }
    }
    __syncthreads();

    // out_proj (8,256)@(128,256)^T -> g_zs
    int b = blk >> 9, k = blk & 511;
#pragma unroll
    for (int r = 0; r < 4; ++r) {
        int e = tid + r * 256;
        int t = e >> 7, i = e & 127;
        const float4* wr = (const float4*)(w_out + i * 256);
        const float4* xr = (const float4*)xcv[t];
        float acc = 0.f;
#pragma unroll 8
        for (int c = 0; c < 64; ++c) {
            float4 w4 = wr[c], x4 = xr[c];
            acc += x4.x * w4.x + x4.y * w4.y + x4.z * w4.z + x4.w * w4.w;
        }
        g_zs[((b * 8 + t) * 512 + k) * 128 + i] = acc;
    }
}

// ---------------- K6: qkv projection, 32 tokens per block ----------------
__global__ __launch_bounds__(256) void k_qkv(const float* __restrict__ wi,
                                             const float* __restrict__ bi) {
    __shared__ float zr[32][128];                 // 16 KB
    int tok0 = blockIdx.x * 32;                   // 1024 blocks
    int tid = threadIdx.x;
#pragma unroll
    for (int r = 0; r < 16; ++r) {
        int e = tid + r * 256;
        zr[e >> 7][e & 127] = g_zs[(size_t)tok0 * 128 + e];
    }
    __syncthreads();
#pragma unroll
    for (int pass = 0; pass < 2; ++pass) {
        int j = tid + pass * 256;
        if (j < 384) {
            const float* wr = wi + j * 128;
            float bv = bi[j];
            float acc[32];
#pragma unroll
            for (int t = 0; t < 32; ++t) acc[t] = bv;
            for (int c = 0; c < 128; ++c) {
                float wv = wr[c];
#pragma unroll
                for (int t = 0; t < 32; ++t) acc[t] += zr[t][c] * wv;
            }
#pragma unroll
            for (int t = 0; t < 32; ++t)
                g_qkv[(size_t)(tok0 + t) * 384 + j] = acc[t];
        }
    }
}

// ---------------- K7: attention per (bt, head); K/V bf16 in LDS ----------------
__global__ __launch_bounds__(512) void k_attn2() {
    __shared__ bf16 kb[512][32];
    __shared__ bf16 vb[512][32];
    int bt = blockIdx.x >> 2;
    int h = blockIdx.x & 3;
    int tid = threadIdx.x;                        // one q token per thread
    const float* Q = g_qkv + (size_t)bt * 512 * 384;
    const float rs = 0.17677669529663687f;        // 1/sqrt(32)

#pragma unroll
    for (int r = 0; r < 32; ++r) {
        int e = tid + r * 512;                    // 16384 = 512 tok × 32 col
        int tok = e >> 5, c = e & 31;
        kb[tok][c] = __float2bfloat16(Q[tok * 384 + 128 + h * 32 + c]);
        vb[tok][c] = __float2bfloat16(Q[tok * 384 + 256 + h * 32 + c]);
    }
    __syncthreads();

    float qv[32];
#pragma unroll
    for (int c = 0; c < 32; ++c) qv[c] = Q[tid * 384 + h * 32 + c] * rs;

    float m = -1e30f, l = 0.f, acc[32];
#pragma unroll
    for (int c = 0; c < 32; ++c) acc[c] = 0.f;
    for (int kk = 0; kk < 512; ++kk) {
        float s = 0.f;
#pragma unroll
        for (int c = 0; c < 32; ++c) s += qv[c] * b2f(kb[kk][c]);
        float mn = fmaxf(m, s);
        float rsc = expf(m - mn);
        float e2 = expf(s - mn);
        l = l * rsc + e2;
#pragma unroll
        for (int c = 0; c < 32; ++c) acc[c] = acc[c] * rsc + e2 * b2f(vb[kk][c]);
        m = mn;
    }
    float inv = 1.f / l;
    float* orow = g_o + ((size_t)bt * 512 + tid) * 128 + h * 32;
#pragma unroll
    for (int c = 0; c < 32; ++c) orow[c] = acc[c] * inv;
}

// ------- K8: out_proj + residual + LayerNorm + scatter (fp32 d_out) -------
__global__ __launch_bounds__(128) void k_final(const float* __restrict__ x_in,
                       float* __restrict__ out,
                       const float* __restrict__ wo, const float* __restrict__ bo,
                       const float* __restrict__ ln_w, const float* __restrict__ ln_b) {
    __shared__ float orow[128];
    __shared__ float sh[4];
    int tk = blockIdx.x;                          // bt*512 + k
    int bt = tk >> 9, k = tk & 511;
    int b = bt >> 3;
    int i = threadIdx.x;                          // 128 threads
    orow[i] = g_o[(size_t)tk * 128 + i];
    __syncthreads();
    const float* wr = wo + i * 128;
    float acc = bo[i];
    for (int j = 0; j < 128; ++j) acc += orow[j] * wr[j];
    float xi = g_zs[(size_t)tk * 128 + i] + acc;
    float s1 = xi, s2 = xi * xi;
#pragma unroll
    for (int off = 32; off; off >>= 1) {
        s1 += __shfl_down(s1, off, 64);
        s2 += __shfl_down(s2, off, 64);
    }
    if ((i & 63) == 0) { sh[(i >> 6) * 2] = s1; sh[(i >> 6) * 2 + 1] = s2; }
    __syncthreads();
    float mu = (sh[0] + sh[2]) * (1.f / 128.f);
    float var = (sh[1] + sh[3]) * (1.f / 128.f) - mu * mu;
    float yo = (xi - mu) * rsqrtf(fmaxf(var, 0.f) + 1e-5f) * ln_w[i] + ln_b[i];
    int n = g_idx[b * KK + k] & 1023;
    size_t oi = (((size_t)(bt * 128 + i)) << 10) + n;
    out[oi] = x_in[oi] + yo;
}

extern "C" void kernel_launch(void* const* d_in, const int* in_sizes, int n_in,
                              void* d_out, int out_size, void* d_ws, size_t ws_size,
                              hipStream_t stream) {
    const float* x_in      = (const float*)d_in[0];
    const float* norm1_w   = (const float*)d_in[1];
    const float* in_proj_w = (const float*)d_in[2];
    const float* conv1d_w  = (const float*)d_in[3];
    const float* conv1d_b  = (const float*)d_in[4];
    const float* x_proj_w  = (const float*)d_in[5];
    const float* dt_proj_w = (const float*)d_in[6];
    const float* dt_proj_b = (const float*)d_in[7];
    const float* A_log     = (const float*)d_in[8];
    const float* Dp        = (const float*)d_in[9];
    const float* out_proj_w= (const float*)d_in[10];
    const float* r1_w      = (const float*)d_in[11];
    const float* r1_b      = (const float*)d_in[12];
    const float* r2_w      = (const float*)d_in[13];
    const float* r2_b      = (const float*)d_in[14];
    const float* attn_in_w = (const float*)d_in[15];
    const float* attn_in_b = (const float*)d_in[16];
    const float* attn_out_w= (const float*)d_in[17];
    const float* attn_out_b= (const float*)d_in[18];
    const float* ln_w      = (const float*)d_in[19];
    const float* ln_b      = (const float*)d_in[20];
    // d_in[21]: current_epoch == 20 (static) -> ratio 0.5 -> K = 512

    float* out = (float*)d_out;

    t_init<<<16, 256, 0, stream>>>(0);
    k_mean<<<4096, 256, 0, stream>>>(x_in);
    k_router_conv<<<1024, 256, 0, stream>>>(r1_w, r1_b);
    k_topk<<<8, 1024, 0, stream>>>(r2_w, r2_b);
    k_copy<<<8192, 256, 0, stream>>>((const float4*)x_in, (float4*)d_out);
    k_gather<<<512, 256, 0, stream>>>(x_in);
    k_mamba<<<4096, 256, 0, stream>>>(norm1_w, in_proj_w, conv1d_w, conv1d_b,
                                      x_proj_w, dt_proj_w, dt_proj_b, A_log, Dp,
                                      out_proj_w);
    k_qkv<<<1024, 256, 0, stream>>>(attn_in_w, attn_in_b);
    k_attn2<<<256, 512, 0, stream>>>();
    k_final<<<32768, 128, 0, stream>>>(x_in, out, attn_out_w, attn_out_b, ln_w, ln_b);
}